// Round 1
// baseline (1082.571 us; speedup 1.0000x reference)
//
#include <hip/hip_runtime.h>
#include <hip/hip_bf16.h>
#include <stdint.h>

// Problem constants (reference: OUT=4096, IN=4096, x = [8,2048,4096] fp32)
#define K_DIM 4096
#define N_DIM 4096
#define M_DIM 16384

// GEMM tile config (m97-verified structure: 128x128 tile, BK=32, 4 waves 2x2)
#define BM 128
#define BN 128
#define BK 32

typedef short short8 __attribute__((ext_vector_type(8)));      // 8 bf16 (4 VGPRs) MFMA A/B frag
typedef float floatx4 __attribute__((ext_vector_type(4)));     // MFMA C/D frag
typedef unsigned short ushort8 __attribute__((ext_vector_type(8)));

typedef __attribute__((address_space(3))) unsigned int lds_u32;
typedef const __attribute__((address_space(1))) unsigned int glb_u32;

__constant__ float NF4_LUT[16] = {
    -1.0f, -0.6961928009986877f, -0.5250730514526367f, -0.39491748809814453f,
    -0.28444138169288635f, -0.18477343022823334f, -0.09105003625154495f, 0.0f,
    0.07958029955625534f, 0.16093020141124725f, 0.24611230194568634f,
    0.33791524171829224f, 0.44070982933044434f, 0.5626170039176941f,
    0.7229568362236023f, 1.0f};

__device__ __forceinline__ unsigned short f2bf(float f) {
    union { float f; unsigned int u; } v; v.f = f;
    return (unsigned short)((v.u + 0x7FFFu + ((v.u >> 16) & 1u)) >> 16);  // RNE
}

// ---- Phase 1: x fp32 -> bf16 (memory-bound; 32B read / 16B write per thread) ----
__global__ __launch_bounds__(256) void cvt_x_kernel(const float4* __restrict__ x4,
                                                    ushort8* __restrict__ xb) {
    int i = blockIdx.x * 256 + threadIdx.x;   // one ushort8 (8 elems) per thread
    float4 a = x4[2 * i];
    float4 b = x4[2 * i + 1];
    ushort8 o;
    o[0] = f2bf(a.x); o[1] = f2bf(a.y); o[2] = f2bf(a.z); o[3] = f2bf(a.w);
    o[4] = f2bf(b.x); o[5] = f2bf(b.y); o[6] = f2bf(b.z); o[7] = f2bf(b.w);
    xb[i] = o;
}

// ---- Phase 2: NF4 unpack -> bf16 W [N][K] (low nibble = elem 2i, high = 2i+1) ----
__global__ __launch_bounds__(256) void dequant_w_kernel(const int4* __restrict__ wp4,
                                                        const float* __restrict__ scale,
                                                        ushort8* __restrict__ wb) {
    __shared__ float lut[16];
    if (threadIdx.x < 16) lut[threadIdx.x] = NF4_LUT[threadIdx.x] * scale[0];
    __syncthreads();
    int i = blockIdx.x * 256 + threadIdx.x;   // 4 packed ints -> 8 bf16 per thread
    int4 p = wp4[i];
    ushort8 o;
    o[0] = f2bf(lut[p.x & 15]); o[1] = f2bf(lut[(p.x >> 4) & 15]);
    o[2] = f2bf(lut[p.y & 15]); o[3] = f2bf(lut[(p.y >> 4) & 15]);
    o[4] = f2bf(lut[p.z & 15]); o[5] = f2bf(lut[(p.z >> 4) & 15]);
    o[6] = f2bf(lut[p.w & 15]); o[7] = f2bf(lut[(p.w >> 4) & 15]);
    wb[i] = o;
}

// ---- Phase 3: C[M][N] = A[M][K] * B[N][K]^T + bias, bf16 MFMA, fp32 out ----
__global__ __launch_bounds__(256) void gemm_bt_kernel(const unsigned short* __restrict__ A,
                                                      const unsigned short* __restrict__ B,
                                                      const float* __restrict__ bias,
                                                      float* __restrict__ C) {
    __shared__ __align__(16) unsigned short lA[BM * BK];  // 8 KB
    __shared__ __align__(16) unsigned short lB[BN * BK];  // 8 KB

    const int t    = threadIdx.x;
    const int wave = t >> 6;
    const int lane = t & 63;
    const int bm0  = blockIdx.y * BM;
    const int bn0  = blockIdx.x * BN;

    const int wm   = (wave >> 1) * 64;   // wave's 64x64 sub-tile
    const int wn   = (wave & 1) * 64;
    const int l15  = lane & 15;
    const int quad = lane >> 4;

    floatx4 acc[4][4];
#pragma unroll
    for (int i = 0; i < 4; ++i)
#pragma unroll
        for (int j = 0; j < 4; ++j)
            acc[i][j] = (floatx4){0.f, 0.f, 0.f, 0.f};

    // Staging: linear 16B-chunk index l = i*256 + t; row = l>>2, chunk = (l&3)*8 bf16.
    // LDS dest must be wave-uniform base + lane*16 (global_load_lds semantics).
    const int rA0 = t >> 2;
    const int cA0 = (t & 3) * 8;
    const unsigned short* gA0 = A + (size_t)(bm0 + rA0) * K_DIM + cA0;
    const unsigned short* gA1 = gA0 + (size_t)64 * K_DIM;            // rows +64
    const unsigned short* gB0 = B + (size_t)(bn0 + rA0) * K_DIM + cA0;
    const unsigned short* gB1 = gB0 + (size_t)64 * K_DIM;

    unsigned short* lA0 = lA + (wave * 64) * 8;          // wave-uniform
    unsigned short* lA1 = lA0 + 256 * 8;
    unsigned short* lB0 = lB + (wave * 64) * 8;
    unsigned short* lB1 = lB0 + 256 * 8;

    for (int k0 = 0; k0 < K_DIM; k0 += BK) {
        __builtin_amdgcn_global_load_lds((glb_u32*)(gA0 + k0), (lds_u32*)lA0, 16, 0, 0);
        __builtin_amdgcn_global_load_lds((glb_u32*)(gA1 + k0), (lds_u32*)lA1, 16, 0, 0);
        __builtin_amdgcn_global_load_lds((glb_u32*)(gB0 + k0), (lds_u32*)lB0, 16, 0, 0);
        __builtin_amdgcn_global_load_lds((glb_u32*)(gB1 + k0), (lds_u32*)lB1, 16, 0, 0);
        __syncthreads();

        short8 af[4], bfr[4];
#pragma unroll
        for (int mi = 0; mi < 4; ++mi)
            af[mi] = *(const short8*)(lA + (wm + mi * 16 + l15) * BK + quad * 8);
#pragma unroll
        for (int ni = 0; ni < 4; ++ni)
            bfr[ni] = *(const short8*)(lB + (wn + ni * 16 + l15) * BK + quad * 8);

#pragma unroll
        for (int mi = 0; mi < 4; ++mi)
#pragma unroll
            for (int ni = 0; ni < 4; ++ni)
                acc[mi][ni] = __builtin_amdgcn_mfma_f32_16x16x32_bf16(
                    af[mi], bfr[ni], acc[mi][ni], 0, 0, 0);

        __syncthreads();
    }

    // Epilogue: D mapping col(n)=lane&15, row(m)=quad*4+reg  [m89-verified]
#pragma unroll
    for (int ni = 0; ni < 4; ++ni) {
        const int n = bn0 + wn + ni * 16 + l15;
        const float bv = bias[n];
#pragma unroll
        for (int mi = 0; mi < 4; ++mi) {
            const int m0 = bm0 + wm + mi * 16 + quad * 4;
            float* cp = C + (size_t)m0 * N_DIM + n;
#pragma unroll
            for (int r = 0; r < 4; ++r)
                cp[(size_t)r * N_DIM] = acc[mi][ni][r] + bv;
        }
    }
}

extern "C" void kernel_launch(void* const* d_in, const int* in_sizes, int n_in,
                              void* d_out, int out_size, void* d_ws, size_t ws_size,
                              hipStream_t stream) {
    const float* x     = (const float*)d_in[0];
    const int*   wp    = (const int*)d_in[1];
    const float* scale = (const float*)d_in[2];
    const float* bias  = (const float*)d_in[3];
    float*       out   = (float*)d_out;

    // ws layout: [0, 128 MiB) x_bf16 ; [128 MiB, 160 MiB) W_bf16
    unsigned short* xb = (unsigned short*)d_ws;
    unsigned short* wb = (unsigned short*)((char*)d_ws + (size_t)M_DIM * K_DIM * 2);

    cvt_x_kernel<<<(M_DIM * (size_t)K_DIM) / 8 / 256, 256, 0, stream>>>(
        (const float4*)x, (ushort8*)xb);
    dequant_w_kernel<<<(N_DIM * (size_t)K_DIM / 2) / 4 / 256, 256, 0, stream>>>(
        (const int4*)wp, scale, (ushort8*)wb);

    dim3 grid(N_DIM / BN, M_DIM / BM);  // (32, 128)
    gemm_bt_kernel<<<grid, 256, 0, stream>>>(xb, wb, bias, out);
}

// Round 2
// 1069.689 us; speedup vs baseline: 1.0120x; 1.0120x over previous
//
#include <hip/hip_runtime.h>
#include <hip/hip_bf16.h>
#include <stdint.h>

// Problem constants (reference: OUT=4096, IN=4096, x = [8,2048,4096] fp32)
#define K_DIM 4096
#define N_DIM 4096
#define M_DIM 16384

// GEMM tile config (m97-verified structure: 128x128 tile, BK=32, 4 waves 2x2)
#define BM 128
#define BN 128
#define BK 32

typedef short short8 __attribute__((ext_vector_type(8)));      // 8 bf16 (4 VGPRs) MFMA A/B frag
typedef float floatx4 __attribute__((ext_vector_type(4)));     // MFMA C/D frag
typedef unsigned short ushort8 __attribute__((ext_vector_type(8)));
typedef unsigned short ushort4v __attribute__((ext_vector_type(4)));

typedef __attribute__((address_space(3))) unsigned int lds_u32;
typedef const __attribute__((address_space(1))) unsigned int glb_u32;

__constant__ float NF4_LUT[16] = {
    -1.0f, -0.6961928009986877f, -0.5250730514526367f, -0.39491748809814453f,
    -0.28444138169288635f, -0.18477343022823334f, -0.09105003625154495f, 0.0f,
    0.07958029955625534f, 0.16093020141124725f, 0.24611230194568634f,
    0.33791524171829224f, 0.44070982933044434f, 0.5626170039176941f,
    0.7229568362236023f, 1.0f};

__device__ __forceinline__ unsigned short f2bf(float f) {
    union { float f; unsigned int u; } v; v.f = f;
    return (unsigned short)((v.u + 0x7FFFu + ((v.u >> 16) & 1u)) >> 16);  // RNE
}

// ---- Phase 1: x fp32 -> bf16. Pure stride-1: 2x dwordx4 load + 2x dwordx2 store ----
__global__ __launch_bounds__(256) void cvt_x_kernel(const float4* __restrict__ x4,
                                                    ushort4v* __restrict__ xb4) {
    int g = blockIdx.x * 256 + threadIdx.x;       // 8 floats per thread
    int i0 = ((g >> 6) << 7) + (g & 63);          // wave-contiguous float4 index
    int i1 = i0 + 64;
    float4 a = x4[i0];
    float4 b = x4[i1];
    ushort4v oa, ob;
    oa[0] = f2bf(a.x); oa[1] = f2bf(a.y); oa[2] = f2bf(a.z); oa[3] = f2bf(a.w);
    ob[0] = f2bf(b.x); ob[1] = f2bf(b.y); ob[2] = f2bf(b.z); ob[3] = f2bf(b.w);
    xb4[i0] = oa;
    xb4[i1] = ob;
}

// ---- Phase 2: NF4 unpack -> bf16 W [N][K] (low nibble = elem 2i, high = 2i+1) ----
__global__ __launch_bounds__(256) void dequant_w_kernel(const int4* __restrict__ wp4,
                                                        const float* __restrict__ scale,
                                                        ushort8* __restrict__ wb) {
    __shared__ float lut[16];
    if (threadIdx.x < 16) lut[threadIdx.x] = NF4_LUT[threadIdx.x] * scale[0];
    __syncthreads();
    int i = blockIdx.x * 256 + threadIdx.x;   // 4 packed ints -> 8 bf16 per thread
    int4 p = wp4[i];
    ushort8 o;
    o[0] = f2bf(lut[p.x & 15]); o[1] = f2bf(lut[(p.x >> 4) & 15]);
    o[2] = f2bf(lut[p.y & 15]); o[3] = f2bf(lut[(p.y >> 4) & 15]);
    o[4] = f2bf(lut[p.z & 15]); o[5] = f2bf(lut[(p.z >> 4) & 15]);
    o[6] = f2bf(lut[p.w & 15]); o[7] = f2bf(lut[(p.w >> 4) & 15]);
    wb[i] = o;
}

// ---- Phase 3: C[M][N] = A[M][K] * B[N][K]^T + bias, bf16 MFMA, fp32 out ----
// LDS chunk-slot XOR swizzle: row r, global 16B-chunk c stored at slot c ^ ((r>>1)&3).
// Staging keeps identity lane->slot (global_load_lds wave-uniform-base constraint);
// the xor is applied to the GLOBAL column instead. Kills the 8-way read conflicts
// (R1: SQ_LDS_BANK_CONFLICT=6.7e7) -> 2-way (free per m136).
__global__ __launch_bounds__(256) void gemm_bt_kernel(const unsigned short* __restrict__ A,
                                                      const unsigned short* __restrict__ B,
                                                      const float* __restrict__ bias,
                                                      float* __restrict__ C) {
    __shared__ __align__(16) unsigned short lA[BM * BK];  // 8 KB
    __shared__ __align__(16) unsigned short lB[BN * BK];  // 8 KB

    const int t    = threadIdx.x;
    const int wave = t >> 6;
    const int lane = t & 63;
    const int bm0  = blockIdx.y * BM;
    const int bn0  = blockIdx.x * BN;

    const int wm   = (wave >> 1) * 64;   // wave's 64x64 sub-tile
    const int wn   = (wave & 1) * 64;
    const int l15  = lane & 15;
    const int quad = lane >> 4;

    floatx4 acc[4][4];
#pragma unroll
    for (int i = 0; i < 4; ++i)
#pragma unroll
        for (int j = 0; j < 4; ++j)
            acc[i][j] = (floatx4){0.f, 0.f, 0.f, 0.f};

    // Staging: thread t -> LDS row t>>2, slot t&3 (identity). Global chunk it must
    // fetch for that slot: (t&3) ^ ((r>>1)&3) = (t&3) ^ ((t>>3)&3).
    const int rA0 = t >> 2;
    const int cA0 = ((t & 3) ^ ((t >> 3) & 3)) * 8;
    const unsigned short* gA0 = A + (size_t)(bm0 + rA0) * K_DIM + cA0;
    const unsigned short* gA1 = gA0 + (size_t)64 * K_DIM;            // rows +64 (same xor term)
    const unsigned short* gB0 = B + (size_t)(bn0 + rA0) * K_DIM + cA0;
    const unsigned short* gB1 = gB0 + (size_t)64 * K_DIM;

    unsigned short* lA0 = lA + (wave * 64) * 8;          // wave-uniform
    unsigned short* lA1 = lA0 + 256 * 8;
    unsigned short* lB0 = lB + (wave * 64) * 8;
    unsigned short* lB1 = lB0 + 256 * 8;

    // Frag-read swizzle: rows are 16k + l15, so ((row>>1)&3) == ((l15>>1)&3).
    const int swz = (l15 >> 1) & 3;
    const int slotA = (quad ^ swz) * 8;   // byte-chunk -> ushort offset

    for (int k0 = 0; k0 < K_DIM; k0 += BK) {
        __builtin_amdgcn_global_load_lds((glb_u32*)(gA0 + k0), (lds_u32*)lA0, 16, 0, 0);
        __builtin_amdgcn_global_load_lds((glb_u32*)(gA1 + k0), (lds_u32*)lA1, 16, 0, 0);
        __builtin_amdgcn_global_load_lds((glb_u32*)(gB0 + k0), (lds_u32*)lB0, 16, 0, 0);
        __builtin_amdgcn_global_load_lds((glb_u32*)(gB1 + k0), (lds_u32*)lB1, 16, 0, 0);
        __syncthreads();

        short8 af[4], bfr[4];
#pragma unroll
        for (int mi = 0; mi < 4; ++mi)
            af[mi] = *(const short8*)(lA + (wm + mi * 16 + l15) * BK + slotA);
#pragma unroll
        for (int ni = 0; ni < 4; ++ni)
            bfr[ni] = *(const short8*)(lB + (wn + ni * 16 + l15) * BK + slotA);

#pragma unroll
        for (int mi = 0; mi < 4; ++mi)
#pragma unroll
            for (int ni = 0; ni < 4; ++ni)
                acc[mi][ni] = __builtin_amdgcn_mfma_f32_16x16x32_bf16(
                    af[mi], bfr[ni], acc[mi][ni], 0, 0, 0);

        __syncthreads();
    }

    // Epilogue: D mapping col(n)=lane&15, row(m)=quad*4+reg  [m89-verified]
#pragma unroll
    for (int ni = 0; ni < 4; ++ni) {
        const int n = bn0 + wn + ni * 16 + l15;
        const float bv = bias[n];
#pragma unroll
        for (int mi = 0; mi < 4; ++mi) {
            const int m0 = bm0 + wm + mi * 16 + quad * 4;
            float* cp = C + (size_t)m0 * N_DIM + n;
#pragma unroll
            for (int r = 0; r < 4; ++r)
                cp[(size_t)r * N_DIM] = acc[mi][ni][r] + bv;
        }
    }
}

extern "C" void kernel_launch(void* const* d_in, const int* in_sizes, int n_in,
                              void* d_out, int out_size, void* d_ws, size_t ws_size,
                              hipStream_t stream) {
    const float* x     = (const float*)d_in[0];
    const int*   wp    = (const int*)d_in[1];
    const float* scale = (const float*)d_in[2];
    const float* bias  = (const float*)d_in[3];
    float*       out   = (float*)d_out;

    // ws layout: [0, 128 MiB) x_bf16 ; [128 MiB, 160 MiB) W_bf16
    unsigned short* xb = (unsigned short*)d_ws;
    unsigned short* wb = (unsigned short*)((char*)d_ws + (size_t)M_DIM * K_DIM * 2);

    cvt_x_kernel<<<(M_DIM * (size_t)K_DIM) / 8 / 256, 256, 0, stream>>>(
        (const float4*)x, (ushort4v*)xb);
    dequant_w_kernel<<<(N_DIM * (size_t)K_DIM / 2) / 4 / 256, 256, 0, stream>>>(
        (const int4*)wp, scale, (ushort8*)wb);

    dim3 grid(N_DIM / BN, M_DIM / BM);  // (32, 128)
    gemm_bt_kernel<<<grid, 256, 0, stream>>>(xb, wb, bias, out);
}